// Round 1
// baseline (824.150 us; speedup 1.0000x reference)
//
#include <hip/hip_runtime.h>
#include <cstdint>

typedef unsigned short u16;
using bf16x8  = __attribute__((ext_vector_type(8))) __bf16;
using floatx4 = __attribute__((ext_vector_type(4))) float;

__device__ __forceinline__ u16 f2bf(float f) {
    uint32_t u = __builtin_bit_cast(uint32_t, f);
    u += 0x7fffu + ((u >> 16) & 1u);   // RNE
    return (u16)(u >> 16);
}
__device__ __forceinline__ float bf2f(u16 h) {
    uint32_t u = ((uint32_t)h) << 16;
    return __builtin_bit_cast(float, u);
}

// ---------------------------------------------------------------------------
// ROIAlign: feat [2,80,80,20,128] f32 -> A1 [50176, 896] bf16, k = z*128+c
// one block per box; 8 point-slots x 32 threads x float4 channels
// ---------------------------------------------------------------------------
__global__ __launch_bounds__(256) void k_roialign(
    const float* __restrict__ feat, const float* __restrict__ boxes,
    const int* __restrict__ bidx, u16* __restrict__ A1)
{
    const int n = blockIdx.x;
    const int t = threadIdx.x;
    const float s = 5.0f; // VOXEL_SCALE * POOLER_SCALE
    const float x1 = boxes[n*6+0]*s, y1 = boxes[n*6+1]*s, z1 = boxes[n*6+2]*s;
    const float x2 = boxes[n*6+3]*s, y2 = boxes[n*6+4]*s, z2 = boxes[n*6+5]*s;
    const float binx = fmaxf(x2-x1, 1.0f) * (1.0f/7.0f);
    const float biny = fmaxf(y2-y1, 1.0f) * (1.0f/7.0f);
    const float binz = fmaxf(z2-z1, 1.0f) * (1.0f/7.0f);
    const int b = bidx[n];
    const float* fb = feat + (size_t)b * 80 * 80 * 20 * 128;
    const int c4   = (t & 31) * 4;
    const int slot = t >> 5;

    for (int p = slot; p < 343; p += 8) {
        const int xq = p / 49;
        const int rem = p - xq * 49;
        const int yq = rem / 7;
        const int zq = rem - yq * 7;
        const float px = x1 + ((float)xq + 0.5f) * binx;
        const float py = y1 + ((float)yq + 0.5f) * biny;
        const float pz = z1 + ((float)zq + 0.5f) * binz;
        const float fx = floorf(px), fy = floorf(py), fz = floorf(pz);
        const float lx = px - fx, ly = py - fy, lz = pz - fz;
        const int xi0 = min(max((int)fx,     0), 79);
        const int xi1 = min(max((int)fx + 1, 0), 79);
        const int yi0 = min(max((int)fy,     0), 79);
        const int yi1 = min(max((int)fy + 1, 0), 79);
        const int zi0 = min(max((int)fz,     0), 19);
        const int zi1 = min(max((int)fz + 1, 0), 19);
        const float wx0 = 1.f-lx, wy0 = 1.f-ly, wz0 = 1.f-lz;
        const float w00 = wx0*wy0, w01 = wx0*ly, w10 = lx*wy0, w11 = lx*ly;
        float a0=0.f, a1=0.f, a2=0.f, a3=0.f;
#define RC(W, XI, YI, ZI) { \
        const float4 v = *(const float4*)(fb + (size_t)(((XI)*80+(YI))*20+(ZI))*128 + c4); \
        a0 = fmaf((W), v.x, a0); a1 = fmaf((W), v.y, a1); \
        a2 = fmaf((W), v.z, a2); a3 = fmaf((W), v.w, a3); }
        RC(w00*wz0, xi0, yi0, zi0); RC(w00*lz, xi0, yi0, zi1);
        RC(w01*wz0, xi0, yi1, zi0); RC(w01*lz, xi0, yi1, zi1);
        RC(w10*wz0, xi1, yi0, zi0); RC(w10*lz, xi1, yi0, zi1);
        RC(w11*wz0, xi1, yi1, zi0); RC(w11*lz, xi1, yi1, zi1);
#undef RC
        const int m = n * 49 + xq * 7 + yq;
        ushort4 o;
        o.x = f2bf(a0); o.y = f2bf(a1); o.z = f2bf(a2); o.w = f2bf(a3);
        *(ushort4*)(A1 + (size_t)m * 896 + zq * 128 + c4) = o;
    }
}

// ---------------------------------------------------------------------------
// conv_w [896,128,7] f32 -> WcT [896 r][896 k] bf16, k = z*128+c
// ---------------------------------------------------------------------------
__global__ __launch_bounds__(256) void k_prep_wc(
    const float* __restrict__ w, u16* __restrict__ out)
{
    const int i = blockIdx.x * 256 + threadIdx.x;   // < 802816 exactly
    const int r = i / 896, k = i % 896;
    const int z = k >> 7, c = k & 127;
    out[i] = f2bf(w[(r * 128 + c) * 7 + z]);
}

// ---------------------------------------------------------------------------
// transpose+cast: in f32 [Kin][896] -> out bf16 [896][Kin]
// PERM=1: out[r][kp] = in[(kp%896)*49 + kp/896][r]  (fc6 k-permutation)
// ---------------------------------------------------------------------------
template <int PERM>
__global__ __launch_bounds__(256) void k_transpose(
    const float* __restrict__ in, u16* __restrict__ out, int Kin)
{
    __shared__ u16 tile[64][72];
    const int kp0 = blockIdx.x * 64, r0 = blockIdx.y * 64;
    const int t = threadIdx.x;
#pragma unroll
    for (int it = 0; it < 16; ++it) {
        const int idx = it * 256 + t;
        const int i = idx >> 6, rl = idx & 63;
        const int kp = kp0 + i;
        const int k = PERM ? (kp % 896) * 49 + (kp / 896) : kp;
        tile[i][rl] = f2bf(in[(size_t)k * 896 + r0 + rl]);
    }
    __syncthreads();
#pragma unroll
    for (int it = 0; it < 16; ++it) {
        const int idx = it * 256 + t;
        const int rl = idx >> 6, i = idx & 63;
        out[(size_t)(r0 + rl) * Kin + kp0 + i] = tile[i][rl];
    }
}

// ---------------------------------------------------------------------------
// GEMM: C[M,N] = A[M,K] * Bt[N,K]^T, bf16 inputs, fp32 accum.
// 128x128 tile, BK=32, 4 waves (2x2), per-wave 4x4 of 16x16x32 MFMA.
// EPI==0: out bf16 = acc + bias[n]; fused BN sum/sumsq atomics. grid.z==1.
// EPI==1: fp32 partial store to outF + blockIdx.z * partStride (split-K).
// ---------------------------------------------------------------------------
template <int EPI>
__global__ __launch_bounds__(256) void k_gemm(
    const u16* __restrict__ A, const u16* __restrict__ Bt,
    float* __restrict__ outF, u16* __restrict__ outH,
    const float* __restrict__ bias, float* __restrict__ bnsum, float* __restrict__ bnsq,
    int Astride, int Bstride, int kpc, int ktot, int partStride)
{
    __shared__ __align__(16) u16 lA[128 * 40];   // pad 32->40: 2-way b128 reads
    __shared__ __align__(16) u16 lB[128 * 40];
    const int t = threadIdx.x;
    const int wave = t >> 6, lane = t & 63;
    const int wm = wave & 1, wn = wave >> 1;
    const int quad = lane >> 4, lr = lane & 15;
    const size_t m0 = (size_t)blockIdx.x * 128;
    const size_t n0 = (size_t)blockIdx.y * 128;
    const int kbeg = blockIdx.z * kpc;
    const int kend = min(kbeg + kpc, ktot);

    floatx4 acc[4][4];
    const floatx4 zero = {0.f, 0.f, 0.f, 0.f};
#pragma unroll
    for (int a = 0; a < 4; ++a)
#pragma unroll
        for (int bq = 0; bq < 4; ++bq) acc[a][bq] = zero;

    const int e0 = t * 8;
    const int r0s = e0 >> 5, c0s = e0 & 31;
    const int e1 = e0 + 2048;
    const int r1s = e1 >> 5, c1s = e1 & 31;
    const u16* Ab = A + m0 * (size_t)Astride;
    const u16* Bb = Bt + n0 * (size_t)Bstride;

    for (int ks = kbeg; ks < kend; ++ks) {
        const size_t k0 = (size_t)ks * 32;
        const uint4 va0 = *(const uint4*)(Ab + (size_t)r0s * Astride + k0 + c0s);
        const uint4 va1 = *(const uint4*)(Ab + (size_t)r1s * Astride + k0 + c1s);
        const uint4 vb0 = *(const uint4*)(Bb + (size_t)r0s * Bstride + k0 + c0s);
        const uint4 vb1 = *(const uint4*)(Bb + (size_t)r1s * Bstride + k0 + c1s);
        __syncthreads();
        *(uint4*)(lA + r0s * 40 + c0s) = va0;
        *(uint4*)(lA + r1s * 40 + c1s) = va1;
        *(uint4*)(lB + r0s * 40 + c0s) = vb0;
        *(uint4*)(lB + r1s * 40 + c1s) = vb1;
        __syncthreads();
        bf16x8 af[4], bfr[4];
#pragma unroll
        for (int mt = 0; mt < 4; ++mt)
            af[mt] = *(const bf16x8*)(lA + (wm * 64 + mt * 16 + lr) * 40 + quad * 8);
#pragma unroll
        for (int nt = 0; nt < 4; ++nt)
            bfr[nt] = *(const bf16x8*)(lB + (wn * 64 + nt * 16 + lr) * 40 + quad * 8);
#pragma unroll
        for (int mt = 0; mt < 4; ++mt)
#pragma unroll
            for (int nt = 0; nt < 4; ++nt)
                acc[mt][nt] = __builtin_amdgcn_mfma_f32_16x16x32_bf16(
                    af[mt], bfr[nt], acc[mt][nt], 0, 0, 0);
    }

    if (EPI == 0) {
#pragma unroll
        for (int nt = 0; nt < 4; ++nt) {
            const int n = (int)n0 + wn * 64 + nt * 16 + lr;
            const float bv = bias[n];
            float s1 = 0.f, s2 = 0.f;
#pragma unroll
            for (int mt = 0; mt < 4; ++mt) {
#pragma unroll
                for (int j = 0; j < 4; ++j) {
                    const int m = (int)m0 + wm * 64 + mt * 16 + quad * 4 + j;
                    const float v = acc[mt][nt][j] + bv;
                    outH[(size_t)m * 896 + n] = f2bf(v);
                    s1 += v;
                    s2 = fmaf(v, v, s2);
                }
            }
            s1 += __shfl_xor(s1, 16); s1 += __shfl_xor(s1, 32);
            s2 += __shfl_xor(s2, 16); s2 += __shfl_xor(s2, 32);
            if (quad == 0) {
                atomicAdd(&bnsum[n], s1);
                atomicAdd(&bnsq[n],  s2);
            }
        }
    } else {
        float* po = outF + (size_t)blockIdx.z * partStride;
#pragma unroll
        for (int nt = 0; nt < 4; ++nt) {
            const int n = (int)n0 + wn * 64 + nt * 16 + lr;
#pragma unroll
            for (int mt = 0; mt < 4; ++mt) {
#pragma unroll
                for (int j = 0; j < 4; ++j) {
                    const int m = (int)m0 + wm * 64 + mt * 16 + quad * 4 + j;
                    po[(size_t)m * 896 + n] = acc[mt][nt][j];
                }
            }
        }
    }
}

// ---------------------------------------------------------------------------
// BN apply + ReLU, in place on y bf16 [50176, 896] (becomes x2)
// ---------------------------------------------------------------------------
__global__ __launch_bounds__(256) void k_bn_apply(
    u16* __restrict__ y, const float* __restrict__ s1, const float* __restrict__ s2,
    const float* __restrict__ gamma, const float* __restrict__ beta)
{
    const size_t i = ((size_t)blockIdx.x * 256 + threadIdx.x) * 8;
    uint4 d = *(const uint4*)(y + i);
    const u16* h = (const u16*)&d;
    const int r0 = (int)(i % 896);
    __align__(16) u16 o[8];
    const float invM = 1.0f / 50176.0f;
#pragma unroll
    for (int j = 0; j < 8; ++j) {
        const int r = r0 + j;
        const float mu  = s1[r] * invM;
        const float var = fmaf(-mu, mu, s2[r] * invM);
        const float rs  = rsqrtf(var + 1e-5f);
        const float v   = (bf2f(h[j]) - mu) * rs * gamma[r] + beta[r];
        o[j] = f2bf(fmaxf(v, 0.f));
    }
    *(uint4*)(y + i) = *(const uint4*)o;
}

// ---------------------------------------------------------------------------
// split-K reduce + bias + relu -> bf16 (fc6 out / GEMM3 input)
// ---------------------------------------------------------------------------
__global__ __launch_bounds__(256) void k_x3(
    const float* __restrict__ part, const float* __restrict__ bias, u16* __restrict__ x3)
{
    const size_t i = ((size_t)blockIdx.x * 256 + threadIdx.x) * 4;
    float a0=0.f, a1=0.f, a2=0.f, a3=0.f;
#pragma unroll
    for (int c = 0; c < 16; ++c) {
        const float4 v = *(const float4*)(part + (size_t)c * 917504 + i);
        a0 += v.x; a1 += v.y; a2 += v.z; a3 += v.w;
    }
    const int r = (int)(i % 896);
    ushort4 o;
    o.x = f2bf(fmaxf(a0 + bias[r+0], 0.f));
    o.y = f2bf(fmaxf(a1 + bias[r+1], 0.f));
    o.z = f2bf(fmaxf(a2 + bias[r+2], 0.f));
    o.w = f2bf(fmaxf(a3 + bias[r+3], 0.f));
    *(ushort4*)(x3 + i) = o;
}

// split-K reduce + bias + relu -> fp32 final output
__global__ __launch_bounds__(256) void k_out(
    const float* __restrict__ part, const float* __restrict__ bias, float* __restrict__ out)
{
    const size_t i = ((size_t)blockIdx.x * 256 + threadIdx.x) * 4;
    float a0=0.f, a1=0.f, a2=0.f, a3=0.f;
#pragma unroll
    for (int c = 0; c < 4; ++c) {
        const float4 v = *(const float4*)(part + (size_t)c * 917504 + i);
        a0 += v.x; a1 += v.y; a2 += v.z; a3 += v.w;
    }
    const int r = (int)(i % 896);
    float4 o;
    o.x = fmaxf(a0 + bias[r+0], 0.f);
    o.y = fmaxf(a1 + bias[r+1], 0.f);
    o.z = fmaxf(a2 + bias[r+2], 0.f);
    o.w = fmaxf(a3 + bias[r+3], 0.f);
    *(float4*)(out + i) = o;
}

// ---------------------------------------------------------------------------
extern "C" void kernel_launch(void* const* d_in, const int* in_sizes, int n_in,
                              void* d_out, int out_size, void* d_ws, size_t ws_size,
                              hipStream_t stream)
{
    (void)in_sizes; (void)n_in; (void)out_size; (void)ws_size;
    const float* features = (const float*)d_in[0];
    const float* boxes    = (const float*)d_in[1];
    const float* conv_w   = (const float*)d_in[2];
    const float* conv_b   = (const float*)d_in[3];
    const float* gamma    = (const float*)d_in[4];
    const float* beta     = (const float*)d_in[5];
    const float* fc6_w    = (const float*)d_in[6];
    const float* fc6_b    = (const float*)d_in[7];
    const float* fc7_w    = (const float*)d_in[8];
    const float* fc7_b    = (const float*)d_in[9];
    const int*   batch_idx = (const int*)d_in[10];
    float* out = (float*)d_out;
    char* ws = (char*)d_ws;

    size_t off = 0;
    auto alloc = [&](size_t b) { size_t o = off; off += (b + 255) & ~(size_t)255; return o; };
    const size_t oA1   = alloc(50176ull * 896 * 2);   // 89,915,392
    const size_t oWcT  = alloc(896ull * 896 * 2);
    const size_t oY    = alloc(50176ull * 896 * 2);
    const size_t oF6T  = alloc(43904ull * 896 * 2);   // 78,675,968
    const size_t oF7T  = alloc(896ull * 896 * 2);
    const size_t oStat = alloc(8192);
    // A1 region is dead after GEMM1 -> reuse for split-K partials + x3
    const size_t oP2 = oA1;                       // 16 * 917504 * 4 = 58,720,256
    const size_t oX3 = oA1 + 58720256;            //  1,835,008
    const size_t oP3 = oX3 + 1835008;             // 14,680,064 (total 75.2 MB < 89.9 MB)

    u16*   A1    = (u16*)(ws + oA1);
    u16*   WcT   = (u16*)(ws + oWcT);
    u16*   Y     = (u16*)(ws + oY);
    u16*   F6T   = (u16*)(ws + oF6T);
    u16*   F7T   = (u16*)(ws + oF7T);
    float* bnsum = (float*)(ws + oStat);
    float* bnsq  = bnsum + 1024;
    float* P2    = (float*)(ws + oP2);
    u16*   X3    = (u16*)(ws + oX3);
    float* P3    = (float*)(ws + oP3);

    // weight prep
    k_prep_wc<<<3136, 256, 0, stream>>>(conv_w, WcT);
    k_transpose<1><<<dim3(686, 14), 256, 0, stream>>>(fc6_w, F6T, 43904);
    k_transpose<0><<<dim3(14, 14), 256, 0, stream>>>(fc7_w, F7T, 896);
    hipMemsetAsync(ws + oStat, 0, 8192, stream);

    // ROIAlign -> A1 [50176, 896] bf16
    k_roialign<<<1024, 256, 0, stream>>>(features, boxes, batch_idx, A1);

    // GEMM1: y = A1 @ WcT^T + conv_b, fused BN stats. M=50176 N=896 K=896
    k_gemm<0><<<dim3(392, 7, 1), 256, 0, stream>>>(
        A1, WcT, nullptr, Y, conv_b, bnsum, bnsq, 896, 896, 28, 28, 0);

    // BN + ReLU in place (Y becomes x2 viewed as [1024, 43904], k'=xy*896+r)
    k_bn_apply<<<21952, 256, 0, stream>>>(Y, bnsum, bnsq, gamma, beta);

    // GEMM2 (fc6): M=1024 N=896 K=43904, split-K 16 -> P2
    k_gemm<1><<<dim3(8, 7, 16), 256, 0, stream>>>(
        Y, F6T, P2, nullptr, nullptr, nullptr, nullptr, 43904, 43904, 86, 1372, 917504);
    k_x3<<<896, 256, 0, stream>>>(P2, fc6_b, X3);

    // GEMM3 (fc7): M=1024 N=896 K=896, split-K 4 -> P3
    k_gemm<1><<<dim3(8, 7, 4), 256, 0, stream>>>(
        X3, F7T, P3, nullptr, nullptr, nullptr, nullptr, 896, 896, 7, 28, 917504);
    k_out<<<896, 256, 0, stream>>>(P3, fc7_b, out);
}